// Round 1
// baseline (52.471 us; speedup 1.0000x reference)
//
#include <hip/hip_runtime.h>

#define DX 160
#define DY 192
#define DZ 160
#define NVOX (DX*DY*DZ)
#define PLANE (DY*DZ)      // 30720 = 120*256 exactly

#define YCHUNK 24
#define YCHUNKS (DY/YCHUNK)   // 8
#define XCHUNK 40
#define XCHUNKS (DX/XCHUNK)   // 4
#define NBLOCKS_B ((PLANE/256)*XCHUNKS)  // 480

__device__ __forceinline__ int iclamp(int v, int hi) {
    return v < 0 ? 0 : (v > hi ? hi : v);
}

// ---------------------------------------------------------------------------
// Kernel A: fused z-box (via LDS line) + y-box (via register shift window).
// Writes 5 arrays layout [q][x][y][z] into ws.
// grid = (DX, YCHUNKS), block = DZ threads (thread = z).
// ---------------------------------------------------------------------------
__global__ __launch_bounds__(DZ) void lcc_boxzy(const float* __restrict__ f,
                                                const float* __restrict__ m,
                                                float* __restrict__ ws) {
    __shared__ float lf[DZ], lm[DZ];
    const int x  = blockIdx.x;
    const int y0 = blockIdx.y * YCHUNK;
    const int z  = threadIdx.x;
    const float* fp = f + (size_t)x * PLANE;
    const float* mp = m + (size_t)x * PLANE;
    float*       wp = ws + (size_t)x * PLANE;

    float h[4][5];   // last 4 z-box lines (statically indexed -> registers)
    float s[5];      // running y-window sums
    #pragma unroll
    for (int q = 0; q < 5; ++q) s[q] = 0.f;
    #pragma unroll
    for (int k = 0; k < 4; ++k)
        #pragma unroll
        for (int q = 0; q < 5; ++q) h[k][q] = 0.f;

    for (int i = 0; i < YCHUNK + 4; ++i) {
        const int yy = iclamp(y0 + i - 2, DY - 1);   // replicate pad in y
        __syncthreads();
        lf[z] = fp[yy * DZ + z];
        lm[z] = mp[yy * DZ + z];
        __syncthreads();

        float L[5] = {0.f, 0.f, 0.f, 0.f, 0.f};
        #pragma unroll
        for (int d = -2; d <= 2; ++d) {
            const int zi = iclamp(z + d, DZ - 1);    // replicate pad in z
            const float fv = lf[zi];
            const float mv = lm[zi];
            L[0] += fv; L[1] += mv; L[2] += fv * mv; L[3] += fv * fv; L[4] += mv * mv;
        }
        #pragma unroll
        for (int q = 0; q < 5; ++q) s[q] += L[q];

        if (i >= 4) {
            const int yc = y0 + i - 4;
            const size_t o = (size_t)yc * DZ + z;
            wp[o]                   = s[0];
            wp[(size_t)NVOX     + o] = s[1];
            wp[(size_t)NVOX * 2 + o] = s[2];
            wp[(size_t)NVOX * 3 + o] = s[3];
            wp[(size_t)NVOX * 4 + o] = s[4];
            #pragma unroll
            for (int q = 0; q < 5; ++q) s[q] -= h[0][q];  // drop oldest line
        }
        // shift history (all indices compile-time constant)
        #pragma unroll
        for (int k = 0; k < 3; ++k)
            #pragma unroll
            for (int q = 0; q < 5; ++q) h[k][q] = h[k + 1][q];
        #pragma unroll
        for (int q = 0; q < 5; ++q) h[3][q] = L[q];
    }
}

// ---------------------------------------------------------------------------
// Kernel B: x-box via register shift window + LCC + deterministic block sum.
// grid = (PLANE/256, XCHUNKS), block = 256 (thread = y*DZ+z, coalesced).
// ---------------------------------------------------------------------------
__global__ __launch_bounds__(256) void lcc_boxx(const float* __restrict__ ws,
                                                float* __restrict__ partials) {
    const int t  = blockIdx.x * 256 + threadIdx.x;   // [0, PLANE)
    const int x0 = blockIdx.y * XCHUNK;

    float h[4][5], s[5];
    #pragma unroll
    for (int q = 0; q < 5; ++q) s[q] = 0.f;
    #pragma unroll
    for (int k = 0; k < 4; ++k)
        #pragma unroll
        for (int q = 0; q < 5; ++q) h[k][q] = 0.f;

    float acc = 0.f;
    for (int i = 0; i < XCHUNK + 4; ++i) {
        const int xx = iclamp(x0 + i - 2, DX - 1);   // replicate pad in x
        const size_t o = (size_t)xx * PLANE + t;
        float L[5];
        L[0] = ws[o];
        L[1] = ws[(size_t)NVOX     + o];
        L[2] = ws[(size_t)NVOX * 2 + o];
        L[3] = ws[(size_t)NVOX * 3 + o];
        L[4] = ws[(size_t)NVOX * 4 + o];
        #pragma unroll
        for (int q = 0; q < 5; ++q) s[q] += L[q];

        if (i >= 4) {
            const float inv = 1.0f / 125.0f;
            const float cross = s[2] - s[0] * s[1] * inv;
            const float fvar  = s[3] - s[0] * s[0] * inv;
            const float mvar  = s[4] - s[1] * s[1] * inv;
            acc += cross * cross / (fvar * mvar + 0.1f);
            #pragma unroll
            for (int q = 0; q < 5; ++q) s[q] -= h[0][q];
        }
        #pragma unroll
        for (int k = 0; k < 3; ++k)
            #pragma unroll
            for (int q = 0; q < 5; ++q) h[k][q] = h[k + 1][q];
        #pragma unroll
        for (int q = 0; q < 5; ++q) h[3][q] = L[q];
    }

    __shared__ float red[256];
    red[threadIdx.x] = acc;
    __syncthreads();
    #pragma unroll
    for (int st = 128; st > 0; st >>= 1) {
        if (threadIdx.x < st) red[threadIdx.x] += red[threadIdx.x + st];
        __syncthreads();
    }
    if (threadIdx.x == 0) partials[blockIdx.y * gridDim.x + blockIdx.x] = red[0];
}

// ---------------------------------------------------------------------------
// Kernel C: deterministic final reduction, writes -sum.
// ---------------------------------------------------------------------------
__global__ __launch_bounds__(256) void lcc_finalize(const float* __restrict__ partials,
                                                    int n, float* __restrict__ out) {
    __shared__ float red[256];
    float a = 0.f;
    for (int i = threadIdx.x; i < n; i += 256) a += partials[i];
    red[threadIdx.x] = a;
    __syncthreads();
    #pragma unroll
    for (int st = 128; st > 0; st >>= 1) {
        if (threadIdx.x < st) red[threadIdx.x] += red[threadIdx.x + st];
        __syncthreads();
    }
    if (threadIdx.x == 0) out[0] = -red[0];
}

// ---------------------------------------------------------------------------
// Fallback: direct 125-tap (only if ws too small for the separable path).
// ---------------------------------------------------------------------------
__global__ __launch_bounds__(256) void lcc_direct(const float* __restrict__ f,
                                                  const float* __restrict__ m,
                                                  float* __restrict__ partials) {
    float acc = 0.f;
    for (int idx = blockIdx.x * 256 + threadIdx.x; idx < NVOX; idx += 256 * gridDim.x) {
        const int z = idx % DZ;
        const int y = (idx / DZ) % DY;
        const int x = idx / PLANE;
        float sf = 0, sm = 0, sfm = 0, sff = 0, smm = 0;
        for (int dx = -2; dx <= 2; ++dx) {
            const int xx = iclamp(x + dx, DX - 1);
            for (int dy = -2; dy <= 2; ++dy) {
                const int yy = iclamp(y + dy, DY - 1);
                const size_t b = (size_t)xx * PLANE + (size_t)yy * DZ;
                #pragma unroll
                for (int dz = -2; dz <= 2; ++dz) {
                    const int zz = iclamp(z + dz, DZ - 1);
                    const float fv = f[b + zz], mv = m[b + zz];
                    sf += fv; sm += mv; sfm += fv * mv; sff += fv * fv; smm += mv * mv;
                }
            }
        }
        const float inv = 1.0f / 125.0f;
        const float cross = sfm - sf * sm * inv;
        const float fvar  = sff - sf * sf * inv;
        const float mvar  = smm - sm * sm * inv;
        acc += cross * cross / (fvar * mvar + 0.1f);
    }
    __shared__ float red[256];
    red[threadIdx.x] = acc;
    __syncthreads();
    #pragma unroll
    for (int st = 128; st > 0; st >>= 1) {
        if (threadIdx.x < st) red[threadIdx.x] += red[threadIdx.x + st];
        __syncthreads();
    }
    if (threadIdx.x == 0) partials[blockIdx.x] = red[0];
}

extern "C" void kernel_launch(void* const* d_in, const int* in_sizes, int n_in,
                              void* d_out, int out_size, void* d_ws, size_t ws_size,
                              hipStream_t stream) {
    const float* f = (const float*)d_in[0];
    const float* m = (const float*)d_in[1];
    float* out = (float*)d_out;

    const size_t need = (size_t)NVOX * 5 * sizeof(float) + (size_t)NBLOCKS_B * sizeof(float);
    if (ws_size >= need) {
        float* ws = (float*)d_ws;
        float* partials = ws + (size_t)NVOX * 5;
        lcc_boxzy<<<dim3(DX, YCHUNKS), DZ, 0, stream>>>(f, m, ws);
        lcc_boxx<<<dim3(PLANE / 256, XCHUNKS), 256, 0, stream>>>(ws, partials);
        lcc_finalize<<<1, 256, 0, stream>>>(partials, NBLOCKS_B, out);
    } else {
        // Fallback: direct 125-tap; only needs nb*4 bytes of scratch.
        const int nb = 2048;
        float* partials = (float*)d_ws;
        lcc_direct<<<nb, 256, 0, stream>>>(f, m, partials);
        lcc_finalize<<<1, 256, 0, stream>>>(partials, nb, out);
    }
}

// Round 2
// 40.039 us; speedup vs baseline: 1.3105x; 1.3105x over previous
//
#include <hip/hip_runtime.h>
#include <hip/hip_fp16.h>

#define DX 160
#define DY 192
#define DZ 160
#define NVOX (DX*DY*DZ)
#define PLANE (DY*DZ)      // 30720 = 120*256 exactly

#define YCHUNK 12
#define YCHUNKS (DY/YCHUNK)   // 16 (two per block)
#define XCHUNK 20
#define XCHUNKS (DX/XCHUNK)   // 8
#define NBLOCKS_B ((PLANE/256)*XCHUNKS)  // 960

__device__ __forceinline__ int iclamp(int v, int hi) {
    return v < 0 ? 0 : (v > hi ? hi : v);
}

// ---------------------------------------------------------------------------
// Kernel A: fused z-box (LDS line) + y-box (register shift ring), fp16 out.
// Block = (160 z-threads) x (2 y-chunks) = 320 threads = 5 full waves.
// grid = (DX, YCHUNKS/2). Writes 5 half arrays layout [q][x][y][z] into ws.
// ---------------------------------------------------------------------------
__global__ __launch_bounds__(320) void lcc_boxzy(const float* __restrict__ f,
                                                 const float* __restrict__ m,
                                                 __half* __restrict__ ws) {
    __shared__ float lf[2][DZ], lm[2][DZ];
    const int x     = blockIdx.x;
    const int ty    = threadIdx.y;
    const int chunk = blockIdx.y * 2 + ty;
    const int y0    = chunk * YCHUNK;
    const int z     = threadIdx.x;
    const float* fp = f + (size_t)x * PLANE;
    const float* mp = m + (size_t)x * PLANE;
    const size_t xbase = (size_t)x * PLANE;

    float h[4][5];   // last 4 z-box lines (fully unrolled loop -> SSA renames)
    float s[5];      // running y-window sums
    #pragma unroll
    for (int q = 0; q < 5; ++q) s[q] = 0.f;
    #pragma unroll
    for (int k = 0; k < 4; ++k)
        #pragma unroll
        for (int q = 0; q < 5; ++q) h[k][q] = 0.f;

    #pragma unroll
    for (int i = 0; i < YCHUNK + 4; ++i) {
        const int yy = iclamp(y0 + i - 2, DY - 1);   // replicate pad in y
        __syncthreads();
        lf[ty][z] = fp[yy * DZ + z];
        lm[ty][z] = mp[yy * DZ + z];
        __syncthreads();

        float L[5] = {0.f, 0.f, 0.f, 0.f, 0.f};
        #pragma unroll
        for (int d = -2; d <= 2; ++d) {
            const int zi = iclamp(z + d, DZ - 1);    // replicate pad in z
            const float fv = lf[ty][zi];
            const float mv = lm[ty][zi];
            L[0] += fv; L[1] += mv; L[2] += fv * mv; L[3] += fv * fv; L[4] += mv * mv;
        }
        #pragma unroll
        for (int q = 0; q < 5; ++q) s[q] += L[q];

        if (i >= 4) {
            const int yc = y0 + i - 4;
            const size_t o = xbase + (size_t)yc * DZ + z;
            #pragma unroll
            for (int q = 0; q < 5; ++q)
                ws[(size_t)q * NVOX + o] = __float2half(s[q]);
            #pragma unroll
            for (int q = 0; q < 5; ++q) s[q] -= h[0][q];  // drop oldest line
        }
        #pragma unroll
        for (int k = 0; k < 3; ++k)
            #pragma unroll
            for (int q = 0; q < 5; ++q) h[k][q] = h[k + 1][q];
        #pragma unroll
        for (int q = 0; q < 5; ++q) h[3][q] = L[q];
    }
}

// ---------------------------------------------------------------------------
// Kernel B: x-box via register shift window + LCC + deterministic block sum.
// grid = (PLANE/256, XCHUNKS), block = 256 (thread = y*DZ+z, coalesced).
// ---------------------------------------------------------------------------
__global__ __launch_bounds__(256) void lcc_boxx(const __half* __restrict__ ws,
                                                float* __restrict__ partials) {
    const int t  = blockIdx.x * 256 + threadIdx.x;   // [0, PLANE)
    const int x0 = blockIdx.y * XCHUNK;

    float h[4][5], s[5];
    #pragma unroll
    for (int q = 0; q < 5; ++q) s[q] = 0.f;
    #pragma unroll
    for (int k = 0; k < 4; ++k)
        #pragma unroll
        for (int q = 0; q < 5; ++q) h[k][q] = 0.f;

    float acc = 0.f;
    for (int i = 0; i < XCHUNK + 4; ++i) {
        const int xx = iclamp(x0 + i - 2, DX - 1);   // replicate pad in x
        const size_t o = (size_t)xx * PLANE + t;
        float L[5];
        #pragma unroll
        for (int q = 0; q < 5; ++q)
            L[q] = __half2float(ws[(size_t)q * NVOX + o]);
        #pragma unroll
        for (int q = 0; q < 5; ++q) s[q] += L[q];

        if (i >= 4) {
            const float inv = 1.0f / 125.0f;
            const float cross = s[2] - s[0] * s[1] * inv;
            const float fvar  = s[3] - s[0] * s[0] * inv;
            const float mvar  = s[4] - s[1] * s[1] * inv;
            acc += cross * cross / (fvar * mvar + 0.1f);
            #pragma unroll
            for (int q = 0; q < 5; ++q) s[q] -= h[0][q];
        }
        #pragma unroll
        for (int k = 0; k < 3; ++k)
            #pragma unroll
            for (int q = 0; q < 5; ++q) h[k][q] = h[k + 1][q];
        #pragma unroll
        for (int q = 0; q < 5; ++q) h[3][q] = L[q];
    }

    __shared__ float red[256];
    red[threadIdx.x] = acc;
    __syncthreads();
    #pragma unroll
    for (int st = 128; st > 0; st >>= 1) {
        if (threadIdx.x < st) red[threadIdx.x] += red[threadIdx.x + st];
        __syncthreads();
    }
    if (threadIdx.x == 0) partials[blockIdx.y * gridDim.x + blockIdx.x] = red[0];
}

// ---------------------------------------------------------------------------
// Kernel C: deterministic final reduction, writes -sum.
// ---------------------------------------------------------------------------
__global__ __launch_bounds__(256) void lcc_finalize(const float* __restrict__ partials,
                                                    int n, float* __restrict__ out) {
    __shared__ float red[256];
    float a = 0.f;
    for (int i = threadIdx.x; i < n; i += 256) a += partials[i];
    red[threadIdx.x] = a;
    __syncthreads();
    #pragma unroll
    for (int st = 128; st > 0; st >>= 1) {
        if (threadIdx.x < st) red[threadIdx.x] += red[threadIdx.x + st];
        __syncthreads();
    }
    if (threadIdx.x == 0) out[0] = -red[0];
}

// ---------------------------------------------------------------------------
// Fallback: direct 125-tap (only if ws too small for the separable path).
// ---------------------------------------------------------------------------
__global__ __launch_bounds__(256) void lcc_direct(const float* __restrict__ f,
                                                  const float* __restrict__ m,
                                                  float* __restrict__ partials) {
    float acc = 0.f;
    for (int idx = blockIdx.x * 256 + threadIdx.x; idx < NVOX; idx += 256 * gridDim.x) {
        const int z = idx % DZ;
        const int y = (idx / DZ) % DY;
        const int x = idx / PLANE;
        float sf = 0, sm = 0, sfm = 0, sff = 0, smm = 0;
        for (int dx = -2; dx <= 2; ++dx) {
            const int xx = iclamp(x + dx, DX - 1);
            for (int dy = -2; dy <= 2; ++dy) {
                const int yy = iclamp(y + dy, DY - 1);
                const size_t b = (size_t)xx * PLANE + (size_t)yy * DZ;
                #pragma unroll
                for (int dz = -2; dz <= 2; ++dz) {
                    const int zz = iclamp(z + dz, DZ - 1);
                    const float fv = f[b + zz], mv = m[b + zz];
                    sf += fv; sm += mv; sfm += fv * mv; sff += fv * fv; smm += mv * mv;
                }
            }
        }
        const float inv = 1.0f / 125.0f;
        const float cross = sfm - sf * sm * inv;
        const float fvar  = sff - sf * sf * inv;
        const float mvar  = smm - sm * sm * inv;
        acc += cross * cross / (fvar * mvar + 0.1f);
    }
    __shared__ float red[256];
    red[threadIdx.x] = acc;
    __syncthreads();
    #pragma unroll
    for (int st = 128; st > 0; st >>= 1) {
        if (threadIdx.x < st) red[threadIdx.x] += red[threadIdx.x + st];
        __syncthreads();
    }
    if (threadIdx.x == 0) partials[blockIdx.x] = red[0];
}

extern "C" void kernel_launch(void* const* d_in, const int* in_sizes, int n_in,
                              void* d_out, int out_size, void* d_ws, size_t ws_size,
                              hipStream_t stream) {
    const float* f = (const float*)d_in[0];
    const float* m = (const float*)d_in[1];
    float* out = (float*)d_out;

    const size_t half_bytes = (size_t)NVOX * 5 * sizeof(__half);  // 49.152 MB
    const size_t need = half_bytes + (size_t)NBLOCKS_B * sizeof(float);
    if (ws_size >= need) {
        __half* ws = (__half*)d_ws;
        float* partials = (float*)((char*)d_ws + half_bytes);
        lcc_boxzy<<<dim3(DX, YCHUNKS / 2), dim3(DZ, 2), 0, stream>>>(f, m, ws);
        lcc_boxx<<<dim3(PLANE / 256, XCHUNKS), 256, 0, stream>>>(ws, partials);
        lcc_finalize<<<1, 256, 0, stream>>>(partials, NBLOCKS_B, out);
    } else {
        // Fallback: direct 125-tap; only needs nb*4 bytes of scratch.
        const int nb = 2048;
        float* partials = (float*)d_ws;
        lcc_direct<<<nb, 256, 0, stream>>>(f, m, partials);
        lcc_finalize<<<1, 256, 0, stream>>>(partials, nb, out);
    }
}